// Round 7
// baseline (612.816 us; speedup 1.0000x reference)
//
#include <hip/hip_runtime.h>
#include <hip/hip_bf16.h>
#include <stdint.h>

#define B_ 4
#define T_ 2048
#define C_ 1024
#define H_ 16
#define D_ 64

typedef __attribute__((ext_vector_type(8))) short bf16x8;
typedef __attribute__((ext_vector_type(4))) short short4v;
typedef __attribute__((ext_vector_type(4))) float f32x4;

static __device__ __forceinline__ short f2bf(float f) {
    union { float f; unsigned u; } v; v.f = f;
    unsigned r = v.u + 0x7fffu + ((v.u >> 16) & 1u);
    return (short)(r >> 16);
}

#define GLD_LDS16(g, l) __builtin_amdgcn_global_load_lds( \
    (const __attribute__((address_space(1))) void*)(g),   \
    (__attribute__((address_space(3))) void*)(l), 16, 0, 0)

// ---------------------------------------------------------------------------
// Packing kernels
// ---------------------------------------------------------------------------
__global__ void pack_x(const float* __restrict__ x, short* __restrict__ xb) {
    int t = blockIdx.x * blockDim.x + threadIdx.x;
    const float* src = x + (size_t)t * 8;
    float4 v0 = *(const float4*)src;
    float4 v1 = *(const float4*)(src + 4);
    bf16x8 o;
    o[0] = f2bf(v0.x); o[1] = f2bf(v0.y); o[2] = f2bf(v0.z); o[3] = f2bf(v0.w);
    o[4] = f2bf(v1.x); o[5] = f2bf(v1.y); o[6] = f2bf(v1.z); o[7] = f2bf(v1.w);
    *(bf16x8*)(xb + (size_t)t * 8) = o;
}

// wq/wk/wv [H][C][D] fp32 -> wqkv_t [N=3072][K=1024] bf16 (B^T), n=qkv*1024+h*64+d
__global__ void pack_wqkv(const float* __restrict__ wq, const float* __restrict__ wk,
                          const float* __restrict__ wv, short* __restrict__ out) {
    int tid = blockIdx.x * blockDim.x + threadIdx.x;
    int n  = tid >> 7;
    int kc = tid & 127;
    int qkv = n >> 10;
    int h = (n >> 6) & 15;
    int d = n & 63;
    const float* w = (qkv == 0) ? wq : (qkv == 1) ? wk : wv;
    const float* src = w + (size_t)h * (C_ * D_) + d;
    short* dst = out + (size_t)n * C_ + kc * 8;
#pragma unroll
    for (int j = 0; j < 8; ++j)
        dst[j] = f2bf(src[(size_t)(kc * 8 + j) * D_]);
}

__global__ void pack_wproj(const float* __restrict__ wp, short* __restrict__ out) {
    int tid = blockIdx.x * blockDim.x + threadIdx.x;
    int n  = tid >> 7;
    int kc = tid & 127;
    short* dst = out + (size_t)n * C_ + kc * 8;
#pragma unroll
    for (int j = 0; j < 8; ++j)
        dst[j] = f2bf(wp[(size_t)(kc * 8 + j) * C_ + n]);
}

// ---------------------------------------------------------------------------
// GEMM (m97 structure). MODE 1: fp32 out + bias.
// MODE 2: QKV split epilogue with anti-camping swizzles:
//   Q (col<1024):      qk[row*2048 + col]                         (plain)
//   K (1024..2047):    qk[row*2048 + 1024 + (c ^ ((row&7)<<7))]   c=col-1024
//   V (>=2048):        vt[(bq*1024+cm)*2048 + (t ^ ((cm&7)<<8))]  transposed
// ---------------------------------------------------------------------------
template<int MODE>
__global__ __launch_bounds__(256)
void gemm_lds(const short* __restrict__ A, const short* __restrict__ Bt,
              void* __restrict__ Cptr, short* __restrict__ vtptr,
              const float* __restrict__ bias, int M, int N, int K) {
    __shared__ short As[128 * 32];
    __shared__ short Bs[128 * 32];
    const int tid = threadIdx.x;
    const int lane = tid & 63, wid = tid >> 6;
    const int wr = wid >> 1, wc = wid & 1;
    const int l15 = lane & 15, l4 = lane >> 4;
    const int m0 = blockIdx.y * 128, n0 = blockIdx.x * 128;

    f32x4 acc[4][4] = {};

    for (int k0 = 0; k0 < K; k0 += 32) {
#pragma unroll
        for (int p = 0; p < 2; ++p) {
            int e = p * 256 + tid;
            int r = e >> 2, c = e & 3;
            GLD_LDS16(A  + (size_t)(m0 + r) * K + k0 + c * 8, As + e * 8);
            GLD_LDS16(Bt + (size_t)(n0 + r) * K + k0 + c * 8, Bs + e * 8);
        }
        __syncthreads();
        bf16x8 af[4], bfr[4];
#pragma unroll
        for (int m = 0; m < 4; ++m)
            af[m] = *(const bf16x8*)(As + (wr * 64 + m * 16 + l15) * 32 + l4 * 8);
#pragma unroll
        for (int n = 0; n < 4; ++n)
            bfr[n] = *(const bf16x8*)(Bs + (wc * 64 + n * 16 + l15) * 32 + l4 * 8);
#pragma unroll
        for (int m = 0; m < 4; ++m)
#pragma unroll
            for (int n = 0; n < 4; ++n)
                acc[m][n] = __builtin_amdgcn_mfma_f32_16x16x32_bf16(af[m], bfr[n], acc[m][n], 0, 0, 0);
        __syncthreads();
    }

#pragma unroll
    for (int m = 0; m < 4; ++m) {
        int row_base = m0 + wr * 64 + m * 16 + l4 * 4;
#pragma unroll
        for (int n = 0; n < 4; ++n) {
            int col = n0 + wc * 64 + n * 16 + l15;
            if (MODE == 1) {
#pragma unroll
                for (int r = 0; r < 4; ++r)
                    ((float*)Cptr)[(size_t)(row_base + r) * N + col] =
                        acc[m][n][r] + bias[col];
            } else {  // MODE 2
                if (n0 < 1024) {            // Q: plain
#pragma unroll
                    for (int r = 0; r < 4; ++r)
                        ((short*)Cptr)[(size_t)(row_base + r) * 2048 + col] = f2bf(acc[m][n][r]);
                } else if (n0 < 2048) {     // K: col-swizzled per row
                    int c = col - 1024;
#pragma unroll
                    for (int r = 0; r < 4; ++r) {
                        int row = row_base + r;
                        ((short*)Cptr)[(size_t)row * 2048 + 1024 + (c ^ ((row & 7) << 7))] =
                            f2bf(acc[m][n][r]);
                    }
                } else {                    // V: transposed + t-swizzled
                    int cm = col - 2048;
                    int bq = row_base >> 11, t = row_base & 2047;
                    int tz = t ^ ((cm & 7) << 8);
                    short4v s;
                    s[0] = f2bf(acc[m][n][0]); s[1] = f2bf(acc[m][n][1]);
                    s[2] = f2bf(acc[m][n][2]); s[3] = f2bf(acc[m][n][3]);
                    *(short4v*)(vtptr + ((size_t)bq * 1024 + cm) * 2048 + tz) = s;
                }
            }
        }
    }
}

// ---------------------------------------------------------------------------
// Flash attention v7: 1-wave blocks, causal-paired strips, no barriers.
// qk: [B*T][2048] bf16 (Q plain | K col-swizzled). vt: [B*H][64][2048] bf16
// (V^T, t-swizzled). Block (pi, bh, ws): 16 q-rows of strip pi and 31-pi.
// ---------------------------------------------------------------------------
__device__ __forceinline__ void softmax_phase(
    f32x4 S[4], f32x4 O[4], float* mrow, float* srow,
    int qrow0, int s0, bool diag, int l15, int l4, short* ps) {
    float pmax[4];
#pragma unroll
    for (int r = 0; r < 4; ++r) pmax[r] = -1e30f;
#pragma unroll
    for (int n = 0; n < 4; ++n) {
#pragma unroll
        for (int r = 0; r < 4; ++r) {
            float v = S[n][r] * 0.03125f;
            if (diag) {
                int scol = s0 + n * 16 + l15;
                if (scol > qrow0 + r) v = -1e30f;
            }
            S[n][r] = v;
            pmax[r] = fmaxf(pmax[r], v);
        }
    }
#pragma unroll
    for (int r = 0; r < 4; ++r) {
        float v = pmax[r];
        v = fmaxf(v, __shfl_xor(v, 1));
        v = fmaxf(v, __shfl_xor(v, 2));
        v = fmaxf(v, __shfl_xor(v, 4));
        v = fmaxf(v, __shfl_xor(v, 8));
        pmax[r] = v;
    }
    float psum[4];
#pragma unroll
    for (int r = 0; r < 4; ++r) {
        float mnew = fmaxf(mrow[r], pmax[r]);
        float fr = __expf(mrow[r] - mnew);
        mrow[r] = mnew;
        srow[r] *= fr;
#pragma unroll
        for (int n = 0; n < 4; ++n) O[n][r] *= fr;
        psum[r] = 0.0f;
    }
#pragma unroll
    for (int n = 0; n < 4; ++n) {
#pragma unroll
        for (int r = 0; r < 4; ++r) {
            float p = __expf(S[n][r] - mrow[r]);
            psum[r] += p;
            ps[(l4 * 4 + r) * 76 + n * 16 + l15] = f2bf(p);
        }
    }
#pragma unroll
    for (int r = 0; r < 4; ++r) {
        float v = psum[r];
        v += __shfl_xor(v, 1);
        v += __shfl_xor(v, 2);
        v += __shfl_xor(v, 4);
        v += __shfl_xor(v, 8);
        srow[r] += v;
    }
}

__global__ __launch_bounds__(64, 4)
void attn_v7(const short* __restrict__ qk, const short* __restrict__ vt,
             short* __restrict__ out) {
    const int pi = blockIdx.x;        // 0..15 (strip pair)
    const int bh = blockIdx.y;        // 0..63
    const int ws = blockIdx.z;        // 0..3 (16-row slice within strip)
    const int b = bh >> 4;
    const int h = bh & 15;
    const int qA0 = pi * 64;
    const int qB0 = (31 - pi) * 64;
    const int ntA = pi + 1;
    const int ntB = 32 - pi;
    const int lane = threadIdx.x;
    const int l15 = lane & 15, l4 = lane >> 4;

    __shared__ short Ps[2][16][76];   // per-strip P buffer (1 wave per block)

    const size_t rs = 2 * C_;  // 2048
    const short* vtb = vt + (size_t)bh * 64 * T_;   // [d][t-swizzled]

    // Q fragments (plain layout)
    const short* qrA = qk + ((size_t)b * T_ + qA0 + ws * 16 + l15) * rs + h * 64;
    const short* qrB = qk + ((size_t)b * T_ + qB0 + ws * 16 + l15) * rs + h * 64;
    bf16x8 aqA0 = *(const bf16x8*)(qrA + l4 * 8);
    bf16x8 aqA1 = *(const bf16x8*)(qrA + 32 + l4 * 8);
    bf16x8 aqB0 = *(const bf16x8*)(qrB + l4 * 8);
    bf16x8 aqB1 = *(const bf16x8*)(qrB + 32 + l4 * 8);

    f32x4 OA[4] = {}, OB[4] = {};
    float mA[4], sA[4], mB[4], sB[4];
#pragma unroll
    for (int r = 0; r < 4; ++r) { mA[r] = mB[r] = -1e30f; sA[r] = sB[r] = 0.0f; }

    short* psB = &Ps[0][0][0];
    short* psA = &Ps[1][0][0];

    const int swzV = (l15 & 7) << 8;  // vt t-swizzle for d-row n*16+l15

    for (int t = 0; t < ntB; ++t) {
        const int s0 = t * 64;
        const bool actA = (t < ntA);

        // ---- K fragments (col-swizzled rows) ----
        bf16x8 bk0[4], bk1[4];
#pragma unroll
        for (int n = 0; n < 4; ++n) {
            const int s = s0 + n * 16 + l15;
            const int swz = (s & 7) << 7;
            const short* kr = qk + ((size_t)b * T_ + s) * rs + 1024;
            bk0[n] = *(const bf16x8*)(kr + ((h * 64 + l4 * 8) ^ swz));
            bk1[n] = *(const bf16x8*)(kr + ((h * 64 + l4 * 8 + 32) ^ swz));
        }
        // ---- V fragments from vt (t-swizzled) ----
        bf16x8 bv0[4], bv1[4];
#pragma unroll
        for (int n = 0; n < 4; ++n) {
            const short* vr = vtb + (size_t)(n * 16 + l15) * T_;
            bv0[n] = *(const bf16x8*)(vr + ((s0 + l4 * 8) ^ swzV));
            bv1[n] = *(const bf16x8*)(vr + ((s0 + 32 + l4 * 8) ^ swzV));
        }

        // ---- strip B: QK^T + softmax ----
        f32x4 S[4];
#pragma unroll
        for (int n = 0; n < 4; ++n) {
            f32x4 z = {};
            z = __builtin_amdgcn_mfma_f32_16x16x32_bf16(aqB0, bk0[n], z, 0, 0, 0);
            S[n] = __builtin_amdgcn_mfma_f32_16x16x32_bf16(aqB1, bk1[n], z, 0, 0, 0);
        }
        softmax_phase(S, OB, mB, sB, qB0 + ws * 16 + l4 * 4, s0, s0 == qB0,
                      l15, l4, psB);

        // ---- strip A ----
        if (actA) {
            f32x4 SA[4];
#pragma unroll
            for (int n = 0; n < 4; ++n) {
                f32x4 z = {};
                z = __builtin_amdgcn_mfma_f32_16x16x32_bf16(aqA0, bk0[n], z, 0, 0, 0);
                SA[n] = __builtin_amdgcn_mfma_f32_16x16x32_bf16(aqA1, bk1[n], z, 0, 0, 0);
            }
            softmax_phase(SA, OA, mA, sA, qA0 + ws * 16 + l4 * 4, s0, s0 == qA0,
                          l15, l4, psA);
        }

        // wave-local ordering: Ps writes land before fragment re-reads
        asm volatile("s_waitcnt lgkmcnt(0)" ::: "memory");
        __builtin_amdgcn_sched_barrier(0);

        // ---- PV strip B ----
        bf16x8 apB0 = *(const bf16x8*)(psB + l15 * 76 + l4 * 8);
        bf16x8 apB1 = *(const bf16x8*)(psB + l15 * 76 + 32 + l4 * 8);
#pragma unroll
        for (int n = 0; n < 4; ++n) {
            OB[n] = __builtin_amdgcn_mfma_f32_16x16x32_bf16(apB0, bv0[n], OB[n], 0, 0, 0);
            OB[n] = __builtin_amdgcn_mfma_f32_16x16x32_bf16(apB1, bv1[n], OB[n], 0, 0, 0);
        }
        // ---- PV strip A ----
        if (actA) {
            bf16x8 apA0 = *(const bf16x8*)(psA + l15 * 76 + l4 * 8);
            bf16x8 apA1 = *(const bf16x8*)(psA + l15 * 76 + 32 + l4 * 8);
#pragma unroll
            for (int n = 0; n < 4; ++n) {
                OA[n] = __builtin_amdgcn_mfma_f32_16x16x32_bf16(apA0, bv0[n], OA[n], 0, 0, 0);
                OA[n] = __builtin_amdgcn_mfma_f32_16x16x32_bf16(apA1, bv1[n], OA[n], 0, 0, 0);
            }
        }
    }

    // ---- normalize + store both strips ----
#pragma unroll
    for (int r = 0; r < 4; ++r) {
        int rowB = qB0 + ws * 16 + l4 * 4 + r;
        int rowA = qA0 + ws * 16 + l4 * 4 + r;
        float invB = 1.0f / sB[r];
        float invA = 1.0f / sA[r];
        size_t obB = ((size_t)b * T_ + rowB) * C_ + h * 64;
        size_t obA = ((size_t)b * T_ + rowA) * C_ + h * 64;
#pragma unroll
        for (int n = 0; n < 4; ++n) {
            out[obB + n * 16 + l15] = f2bf(OB[n][r] * invB);
            out[obA + n * 16 + l15] = f2bf(OA[n][r] * invA);
        }
    }
}

// ---------------------------------------------------------------------------
extern "C" void kernel_launch(void* const* d_in, const int* in_sizes, int n_in,
                              void* d_out, int out_size, void* d_ws, size_t ws_size,
                              hipStream_t stream) {
    const float* x     = (const float*)d_in[0];
    const float* wq    = (const float*)d_in[1];
    const float* wk    = (const float*)d_in[2];
    const float* wv    = (const float*)d_in[3];
    const float* wproj = (const float*)d_in[4];
    const float* bproj = (const float*)d_in[5];
    float* out = (float*)d_out;

    // workspace (shorts): wqkv_t | wproj_t | qk_b | vt | attn_b (xb alias)
    short* wqkv_t  = (short*)d_ws;                   // 3072*1024
    short* wproj_t = wqkv_t + 3072 * 1024;           // 1024*1024
    short* qk_b    = wproj_t + 1024 * 1024;          // 8192*2048  (Q|K)
    short* vt_b    = qk_b + (size_t)8192 * 2048;     // 64*64*2048 (V^T)
    short* attn_b  = vt_b + (size_t)64 * 64 * 2048;  // 8192*1024 (xb alias)
    short* xb      = attn_b;
    // total = 75,497,472 bytes (same as rounds 1-6)

    pack_x<<<4096, 256, 0, stream>>>(x, xb);
    pack_wqkv<<<1536, 256, 0, stream>>>(wq, wk, wv, wqkv_t);
    pack_wproj<<<512, 256, 0, stream>>>(wproj, wproj_t);

    // QKV projection with split epilogue: Q plain | K swizzled | V^T swizzled
    gemm_lds<2><<<dim3(24, 64), 256, 0, stream>>>(
        xb, wqkv_t, qk_b, vt_b, nullptr, 8192, 3072, 1024);

    // flash attention: 1-wave blocks, no barriers
    attn_v7<<<dim3(16, 64, 4), 64, 0, stream>>>(qk_b, vt_b, attn_b);

    // output projection: [8192,1024] x [1024,1024] + bias -> fp32
    gemm_lds<1><<<dim3(8, 64), 256, 0, stream>>>(
        attn_b, wproj_t, out, nullptr, bproj, 8192, 1024, 1024);
}

// Round 8
// 340.316 us; speedup vs baseline: 1.8007x; 1.8007x over previous
//
#include <hip/hip_runtime.h>
#include <hip/hip_bf16.h>
#include <stdint.h>

#define B_ 4
#define T_ 2048
#define C_ 1024
#define H_ 16
#define D_ 64

typedef __attribute__((ext_vector_type(8))) short bf16x8;
typedef __attribute__((ext_vector_type(4))) float f32x4;

static __device__ __forceinline__ short f2bf(float f) {
    union { float f; unsigned u; } v; v.f = f;
    unsigned r = v.u + 0x7fffu + ((v.u >> 16) & 1u);
    return (short)(r >> 16);
}

#define GLD_LDS16(g, l) __builtin_amdgcn_global_load_lds( \
    (const __attribute__((address_space(1))) void*)(g),   \
    (__attribute__((address_space(3))) void*)(l), 16, 0, 0)

// ---------------------------------------------------------------------------
// Packing kernels (round-5 exact)
// ---------------------------------------------------------------------------
__global__ void pack_x(const float* __restrict__ x, short* __restrict__ xb) {
    int t = blockIdx.x * blockDim.x + threadIdx.x;
    const float* src = x + (size_t)t * 8;
    float4 v0 = *(const float4*)src;
    float4 v1 = *(const float4*)(src + 4);
    bf16x8 o;
    o[0] = f2bf(v0.x); o[1] = f2bf(v0.y); o[2] = f2bf(v0.z); o[3] = f2bf(v0.w);
    o[4] = f2bf(v1.x); o[5] = f2bf(v1.y); o[6] = f2bf(v1.z); o[7] = f2bf(v1.w);
    *(bf16x8*)(xb + (size_t)t * 8) = o;
}

__global__ void pack_wqkv(const float* __restrict__ wq, const float* __restrict__ wk,
                          const float* __restrict__ wv, short* __restrict__ out) {
    int tid = blockIdx.x * blockDim.x + threadIdx.x;
    int n  = tid >> 7;
    int kc = tid & 127;
    int qkv = n >> 10;
    int h = (n >> 6) & 15;
    int d = n & 63;
    const float* w = (qkv == 0) ? wq : (qkv == 1) ? wk : wv;
    const float* src = w + (size_t)h * (C_ * D_) + d;
    short* dst = out + (size_t)n * C_ + kc * 8;
#pragma unroll
    for (int j = 0; j < 8; ++j)
        dst[j] = f2bf(src[(size_t)(kc * 8 + j) * D_]);
}

__global__ void pack_wproj(const float* __restrict__ wp, short* __restrict__ out) {
    int tid = blockIdx.x * blockDim.x + threadIdx.x;
    int n  = tid >> 7;
    int kc = tid & 127;
    short* dst = out + (size_t)n * C_ + kc * 8;
#pragma unroll
    for (int j = 0; j < 8; ++j)
        dst[j] = f2bf(wp[(size_t)(kc * 8 + j) * C_ + n]);
}

// ---------------------------------------------------------------------------
// GEMM (m97 structure, round-5 exact)
// ---------------------------------------------------------------------------
template<bool OUT_F32>
__global__ __launch_bounds__(256)
void gemm_lds(const short* __restrict__ A, const short* __restrict__ Bt,
              void* __restrict__ Cptr, const float* __restrict__ bias,
              int M, int N, int K) {
    __shared__ short As[128 * 32];
    __shared__ short Bs[128 * 32];
    const int tid = threadIdx.x;
    const int lane = tid & 63, wid = tid >> 6;
    const int wr = wid >> 1, wc = wid & 1;
    const int l15 = lane & 15, l4 = lane >> 4;
    const int m0 = blockIdx.y * 128, n0 = blockIdx.x * 128;

    f32x4 acc[4][4] = {};

    for (int k0 = 0; k0 < K; k0 += 32) {
#pragma unroll
        for (int p = 0; p < 2; ++p) {
            int e = p * 256 + tid;
            int r = e >> 2, c = e & 3;
            GLD_LDS16(A  + (size_t)(m0 + r) * K + k0 + c * 8, As + e * 8);
            GLD_LDS16(Bt + (size_t)(n0 + r) * K + k0 + c * 8, Bs + e * 8);
        }
        __syncthreads();
        bf16x8 af[4], bfr[4];
#pragma unroll
        for (int m = 0; m < 4; ++m)
            af[m] = *(const bf16x8*)(As + (wr * 64 + m * 16 + l15) * 32 + l4 * 8);
#pragma unroll
        for (int n = 0; n < 4; ++n)
            bfr[n] = *(const bf16x8*)(Bs + (wc * 64 + n * 16 + l15) * 32 + l4 * 8);
#pragma unroll
        for (int m = 0; m < 4; ++m)
#pragma unroll
            for (int n = 0; n < 4; ++n)
                acc[m][n] = __builtin_amdgcn_mfma_f32_16x16x32_bf16(af[m], bfr[n], acc[m][n], 0, 0, 0);
        __syncthreads();
    }

#pragma unroll
    for (int m = 0; m < 4; ++m) {
        int row_base = m0 + wr * 64 + m * 16 + l4 * 4;
#pragma unroll
        for (int n = 0; n < 4; ++n) {
            int col = n0 + wc * 64 + n * 16 + l15;
#pragma unroll
            for (int r = 0; r < 4; ++r) {
                int row = row_base + r;
                float v = acc[m][n][r];
                if (OUT_F32) {
                    ((float*)Cptr)[(size_t)row * N + col] = v + (bias ? bias[col] : 0.0f);
                } else {
                    ((short*)Cptr)[(size_t)row * N + col] = f2bf(v);
                }
            }
        }
    }
}

// ---------------------------------------------------------------------------
// Flash attention v8: v5 structure (paired strips, 4 waves) with
//  - 1 barrier/tile (double-buffered Vt, async V-stage split)
//  - conflict-free Vt: linear [2][64][64], chunk-XOR c^=(row&7) both sides
//  - Ps stride 76; setprio around MFMA clusters
// ---------------------------------------------------------------------------
__device__ __forceinline__ void softmax_phase(
    f32x4 S[4], f32x4 O[4], float* mrow, float* srow,
    int qrow0, int s0, bool diag, int l15, int l4, short* ps) {
    float pmax[4];
#pragma unroll
    for (int r = 0; r < 4; ++r) pmax[r] = -1e30f;
#pragma unroll
    for (int n = 0; n < 4; ++n) {
#pragma unroll
        for (int r = 0; r < 4; ++r) {
            float v = S[n][r] * 0.03125f;
            if (diag) {
                int scol = s0 + n * 16 + l15;
                if (scol > qrow0 + r) v = -1e30f;
            }
            S[n][r] = v;
            pmax[r] = fmaxf(pmax[r], v);
        }
    }
#pragma unroll
    for (int r = 0; r < 4; ++r) {
        float v = pmax[r];
        v = fmaxf(v, __shfl_xor(v, 1));
        v = fmaxf(v, __shfl_xor(v, 2));
        v = fmaxf(v, __shfl_xor(v, 4));
        v = fmaxf(v, __shfl_xor(v, 8));
        pmax[r] = v;
    }
    float psum[4];
#pragma unroll
    for (int r = 0; r < 4; ++r) {
        float mnew = fmaxf(mrow[r], pmax[r]);
        float fr = __expf(mrow[r] - mnew);
        mrow[r] = mnew;
        srow[r] *= fr;
#pragma unroll
        for (int n = 0; n < 4; ++n) O[n][r] *= fr;
        psum[r] = 0.0f;
    }
#pragma unroll
    for (int n = 0; n < 4; ++n) {
#pragma unroll
        for (int r = 0; r < 4; ++r) {
            float p = __expf(S[n][r] - mrow[r]);
            psum[r] += p;
            ps[(l4 * 4 + r) * 76 + n * 16 + l15] = f2bf(p);
        }
    }
#pragma unroll
    for (int r = 0; r < 4; ++r) {
        float v = psum[r];
        v += __shfl_xor(v, 1);
        v += __shfl_xor(v, 2);
        v += __shfl_xor(v, 4);
        v += __shfl_xor(v, 8);
        srow[r] += v;
    }
}

__global__ __launch_bounds__(256)
void attn_v8(const short* __restrict__ qkv, short* __restrict__ out) {
    const int pi = blockIdx.x;        // 0..15 (strip pair)
    const int bh = blockIdx.y;        // 0..63
    const int b = bh >> 4;
    const int h = bh & 15;
    const int qA0 = pi * 64;
    const int qB0 = (31 - pi) * 64;
    const int ntA = pi + 1;
    const int ntB = 32 - pi;
    const int tid = threadIdx.x;
    const int wave = tid >> 6;
    const int lane = tid & 63;
    const int l15 = lane & 15, l4 = lane >> 4;

    __shared__ short Vt[2][64][64];     // Vt[buf][d][s], chunk-XOR swizzled
    __shared__ short Ps[4][2][16][76];  // per-wave, per-strip P buffer

    const size_t rs = 3 * C_;
    const short* qbA = qkv + ((size_t)b * T_ + qA0) * rs + h * 64;
    const short* qbB = qkv + ((size_t)b * T_ + qB0) * rs + h * 64;
    const short* kb  = qkv + (size_t)b * T_ * rs + C_ + h * 64;
    const short* vb  = qkv + (size_t)b * T_ * rs + 2 * C_ + h * 64;

    bf16x8 aqA0 = *(const bf16x8*)(qbA + (size_t)(wave * 16 + l15) * rs + l4 * 8);
    bf16x8 aqA1 = *(const bf16x8*)(qbA + (size_t)(wave * 16 + l15) * rs + 32 + l4 * 8);
    bf16x8 aqB0 = *(const bf16x8*)(qbB + (size_t)(wave * 16 + l15) * rs + l4 * 8);
    bf16x8 aqB1 = *(const bf16x8*)(qbB + (size_t)(wave * 16 + l15) * rs + 32 + l4 * 8);

    f32x4 OA[4] = {}, OB[4] = {};
    float mA[4], sA[4], mB[4], sB[4];
#pragma unroll
    for (int r = 0; r < 4; ++r) { mA[r] = mB[r] = -1e30f; sA[r] = sB[r] = 0.0f; }

    short* psB = &Ps[wave][0][0][0];
    short* psA = &Ps[wave][1][0][0];

    // V staging mapping: this thread owns row d=lane, chunks sc0=wave, sc1=4+wave
    const int vd = lane;
    const int sc0 = wave, sc1 = 4 + wave;
    const int pc0 = (sc0 ^ (vd & 7)) * 8;   // physical chunk offsets (swizzled)
    const int pc1 = (sc1 ^ (vd & 7)) * 8;

    bf16x8 vreg0, vreg1;
    // prologue: load + write tile 0 into buf 0
#pragma unroll
    for (int j = 0; j < 8; ++j) {
        vreg0[j] = vb[(size_t)(sc0 * 8 + j) * rs + vd];
        vreg1[j] = vb[(size_t)(sc1 * 8 + j) * rs + vd];
    }
    *(bf16x8*)&Vt[0][vd][pc0] = vreg0;
    *(bf16x8*)&Vt[0][vd][pc1] = vreg1;

    for (int t = 0; t < ntB; ++t) {
        const int s0 = t * 64;
        const int cur = t & 1;
        const bool actA = (t < ntA);
        const bool pre = (t + 1 < ntB);

        __syncthreads();  // prev PV done (buf cur^1 free); buf cur writes visible

        // ---- issue V(t+1) global loads early (latency hides under compute) ----
        if (pre) {
#pragma unroll
            for (int j = 0; j < 8; ++j) {
                vreg0[j] = vb[(size_t)(s0 + 64 + sc0 * 8 + j) * rs + vd];
                vreg1[j] = vb[(size_t)(s0 + 64 + sc1 * 8 + j) * rs + vd];
            }
        }

        // ---- K fragments (shared by both strips) ----
        bf16x8 bk0[4], bk1[4];
#pragma unroll
        for (int n = 0; n < 4; ++n) {
            const short* kr = kb + (size_t)(s0 + n * 16 + l15) * rs;
            bk0[n] = *(const bf16x8*)(kr + l4 * 8);
            bk1[n] = *(const bf16x8*)(kr + 32 + l4 * 8);
        }

        // ---- strip B: QK^T + softmax ----
        f32x4 S[4];
        __builtin_amdgcn_s_setprio(1);
#pragma unroll
        for (int n = 0; n < 4; ++n) {
            f32x4 z = {};
            z = __builtin_amdgcn_mfma_f32_16x16x32_bf16(aqB0, bk0[n], z, 0, 0, 0);
            S[n] = __builtin_amdgcn_mfma_f32_16x16x32_bf16(aqB1, bk1[n], z, 0, 0, 0);
        }
        __builtin_amdgcn_s_setprio(0);
        softmax_phase(S, OB, mB, sB, qB0 + wave * 16 + l4 * 4, s0, s0 == qB0,
                      l15, l4, psB);

        // ---- strip A ----
        if (actA) {
            f32x4 SA[4];
            __builtin_amdgcn_s_setprio(1);
#pragma unroll
            for (int n = 0; n < 4; ++n) {
                f32x4 z = {};
                z = __builtin_amdgcn_mfma_f32_16x16x32_bf16(aqA0, bk0[n], z, 0, 0, 0);
                SA[n] = __builtin_amdgcn_mfma_f32_16x16x32_bf16(aqA1, bk1[n], z, 0, 0, 0);
            }
            __builtin_amdgcn_s_setprio(0);
            softmax_phase(SA, OA, mA, sA, qA0 + wave * 16 + l4 * 4, s0, s0 == qA0,
                          l15, l4, psA);
        }

        // ---- write V(t+1) into the other buffer (vmcnt auto-wait on vregs) ----
        if (pre) {
            *(bf16x8*)&Vt[cur ^ 1][vd][pc0] = vreg0;
            *(bf16x8*)&Vt[cur ^ 1][vd][pc1] = vreg1;
        }

        // wave-local: Ps writes land before fragment re-reads
        asm volatile("s_waitcnt lgkmcnt(0)" ::: "memory");
        __builtin_amdgcn_sched_barrier(0);

        // ---- PV (swizzled Vt reads, conflict-free) ----
        bf16x8 apB0 = *(const bf16x8*)(psB + l15 * 76 + l4 * 8);
        bf16x8 apB1 = *(const bf16x8*)(psB + l15 * 76 + 32 + l4 * 8);
        __builtin_amdgcn_s_setprio(1);
#pragma unroll
        for (int n = 0; n < 4; ++n) {
            const short* vrow = &Vt[cur][n * 16 + l15][0];
            bf16x8 bv0 = *(const bf16x8*)(vrow + ((l4 ^ (l15 & 7)) * 8));
            bf16x8 bv1 = *(const bf16x8*)(vrow + (((l4 + 4) ^ (l15 & 7)) * 8));
            OB[n] = __builtin_amdgcn_mfma_f32_16x16x32_bf16(apB0, bv0, OB[n], 0, 0, 0);
            OB[n] = __builtin_amdgcn_mfma_f32_16x16x32_bf16(apB1, bv1, OB[n], 0, 0, 0);
        }
        __builtin_amdgcn_s_setprio(0);
        if (actA) {
            bf16x8 apA0 = *(const bf16x8*)(psA + l15 * 76 + l4 * 8);
            bf16x8 apA1 = *(const bf16x8*)(psA + l15 * 76 + 32 + l4 * 8);
            __builtin_amdgcn_s_setprio(1);
#pragma unroll
            for (int n = 0; n < 4; ++n) {
                const short* vrow = &Vt[cur][n * 16 + l15][0];
                bf16x8 bv0 = *(const bf16x8*)(vrow + ((l4 ^ (l15 & 7)) * 8));
                bf16x8 bv1 = *(const bf16x8*)(vrow + (((l4 + 4) ^ (l15 & 7)) * 8));
                OA[n] = __builtin_amdgcn_mfma_f32_16x16x32_bf16(apA0, bv0, OA[n], 0, 0, 0);
                OA[n] = __builtin_amdgcn_mfma_f32_16x16x32_bf16(apA1, bv1, OA[n], 0, 0, 0);
            }
            __builtin_amdgcn_s_setprio(0);
        }
    }

    // ---- normalize + store both strips ----
#pragma unroll
    for (int r = 0; r < 4; ++r) {
        int rowB = qB0 + wave * 16 + l4 * 4 + r;
        int rowA = qA0 + wave * 16 + l4 * 4 + r;
        float invB = 1.0f / sB[r];
        float invA = 1.0f / sA[r];
        size_t obB = ((size_t)b * T_ + rowB) * C_ + h * 64;
        size_t obA = ((size_t)b * T_ + rowA) * C_ + h * 64;
#pragma unroll
        for (int n = 0; n < 4; ++n) {
            out[obB + n * 16 + l15] = f2bf(OB[n][r] * invB);
            out[obA + n * 16 + l15] = f2bf(OA[n][r] * invA);
        }
    }
}

// ---------------------------------------------------------------------------
extern "C" void kernel_launch(void* const* d_in, const int* in_sizes, int n_in,
                              void* d_out, int out_size, void* d_ws, size_t ws_size,
                              hipStream_t stream) {
    const float* x     = (const float*)d_in[0];
    const float* wq    = (const float*)d_in[1];
    const float* wk    = (const float*)d_in[2];
    const float* wv    = (const float*)d_in[3];
    const float* wproj = (const float*)d_in[4];
    const float* bproj = (const float*)d_in[5];
    float* out = (float*)d_out;

    // workspace layout (shorts): wqkv_t | wproj_t | qkv | attn_b (also xb)
    short* wqkv_t  = (short*)d_ws;                  // 3072*1024
    short* wproj_t = wqkv_t + 3072 * 1024;          // 1024*1024
    short* qkv_b   = wproj_t + 1024 * 1024;         // 8192*3072
    short* attn_b  = qkv_b + (size_t)8192 * 3072;   // 8192*1024 (xb aliased here)
    short* xb      = attn_b;                        // x bf16, dead after gemm1
    // total = 75,497,472 bytes

    pack_x<<<4096, 256, 0, stream>>>(x, xb);
    pack_wqkv<<<1536, 256, 0, stream>>>(wq, wk, wv, wqkv_t);
    pack_wproj<<<512, 256, 0, stream>>>(wproj, wproj_t);

    // QKV projection: [8192,1024] x [1024,3072] -> bf16
    gemm_lds<false><<<dim3(24, 64), 256, 0, stream>>>(
        xb, wqkv_t, qkv_b, nullptr, 8192, 3072, 1024);

    // flash attention, causal-paired strips, 1 barrier/tile
    attn_v8<<<dim3(16, 64), 256, 0, stream>>>(qkv_b, attn_b);

    // output projection: [8192,1024] x [1024,1024] + bias -> fp32
    gemm_lds<true><<<dim3(8, 64), 256, 0, stream>>>(
        attn_b, wproj_t, out, bproj, 8192, 1024, 1024);
}

// Round 9
// 333.329 us; speedup vs baseline: 1.8385x; 1.0210x over previous
//
#include <hip/hip_runtime.h>
#include <hip/hip_bf16.h>
#include <stdint.h>

#define B_ 4
#define T_ 2048
#define C_ 1024
#define H_ 16
#define D_ 64

typedef __attribute__((ext_vector_type(8))) short bf16x8;
typedef __attribute__((ext_vector_type(4))) float f32x4;

static __device__ __forceinline__ short f2bf(float f) {
    union { float f; unsigned u; } v; v.f = f;
    unsigned r = v.u + 0x7fffu + ((v.u >> 16) & 1u);
    return (short)(r >> 16);
}

static __device__ __forceinline__ float fast_exp2(float x) {
    float r;
    asm("v_exp_f32 %0, %1" : "=v"(r) : "v"(x));
    return r;
}

#define GLD_LDS16(g, l) __builtin_amdgcn_global_load_lds( \
    (const __attribute__((address_space(1))) void*)(g),   \
    (__attribute__((address_space(3))) void*)(l), 16, 0, 0)

// Q pre-scale: (1/32) * log2(e)  — folds softmax scale AND exp->exp2 conversion
#define QSCALE 0.04508422f

// ---------------------------------------------------------------------------
// Packing kernels (round-5 exact)
// ---------------------------------------------------------------------------
__global__ void pack_x(const float* __restrict__ x, short* __restrict__ xb) {
    int t = blockIdx.x * blockDim.x + threadIdx.x;
    const float* src = x + (size_t)t * 8;
    float4 v0 = *(const float4*)src;
    float4 v1 = *(const float4*)(src + 4);
    bf16x8 o;
    o[0] = f2bf(v0.x); o[1] = f2bf(v0.y); o[2] = f2bf(v0.z); o[3] = f2bf(v0.w);
    o[4] = f2bf(v1.x); o[5] = f2bf(v1.y); o[6] = f2bf(v1.z); o[7] = f2bf(v1.w);
    *(bf16x8*)(xb + (size_t)t * 8) = o;
}

__global__ void pack_wqkv(const float* __restrict__ wq, const float* __restrict__ wk,
                          const float* __restrict__ wv, short* __restrict__ out) {
    int tid = blockIdx.x * blockDim.x + threadIdx.x;
    int n  = tid >> 7;
    int kc = tid & 127;
    int qkv = n >> 10;
    int h = (n >> 6) & 15;
    int d = n & 63;
    const float* w = (qkv == 0) ? wq : (qkv == 1) ? wk : wv;
    const float* src = w + (size_t)h * (C_ * D_) + d;
    short* dst = out + (size_t)n * C_ + kc * 8;
#pragma unroll
    for (int j = 0; j < 8; ++j)
        dst[j] = f2bf(src[(size_t)(kc * 8 + j) * D_]);
}

__global__ void pack_wproj(const float* __restrict__ wp, short* __restrict__ out) {
    int tid = blockIdx.x * blockDim.x + threadIdx.x;
    int n  = tid >> 7;
    int kc = tid & 127;
    short* dst = out + (size_t)n * C_ + kc * 8;
#pragma unroll
    for (int j = 0; j < 8; ++j)
        dst[j] = f2bf(wp[(size_t)(kc * 8 + j) * C_ + n]);
}

// ---------------------------------------------------------------------------
// GEMM (m97 structure). MODE 1: fp32 out + bias.
// MODE 2: bf16 out; Q columns (col<1024) pre-scaled by QSCALE (exp2-domain
// softmax fold — free multiply in the epilogue).
// ---------------------------------------------------------------------------
template<int MODE>
__global__ __launch_bounds__(256)
void gemm_lds(const short* __restrict__ A, const short* __restrict__ Bt,
              void* __restrict__ Cptr, const float* __restrict__ bias,
              int M, int N, int K) {
    __shared__ short As[128 * 32];
    __shared__ short Bs[128 * 32];
    const int tid = threadIdx.x;
    const int lane = tid & 63, wid = tid >> 6;
    const int wr = wid >> 1, wc = wid & 1;
    const int l15 = lane & 15, l4 = lane >> 4;
    const int m0 = blockIdx.y * 128, n0 = blockIdx.x * 128;

    f32x4 acc[4][4] = {};

    for (int k0 = 0; k0 < K; k0 += 32) {
#pragma unroll
        for (int p = 0; p < 2; ++p) {
            int e = p * 256 + tid;
            int r = e >> 2, c = e & 3;
            GLD_LDS16(A  + (size_t)(m0 + r) * K + k0 + c * 8, As + e * 8);
            GLD_LDS16(Bt + (size_t)(n0 + r) * K + k0 + c * 8, Bs + e * 8);
        }
        __syncthreads();
        bf16x8 af[4], bfr[4];
#pragma unroll
        for (int m = 0; m < 4; ++m)
            af[m] = *(const bf16x8*)(As + (wr * 64 + m * 16 + l15) * 32 + l4 * 8);
#pragma unroll
        for (int n = 0; n < 4; ++n)
            bfr[n] = *(const bf16x8*)(Bs + (wc * 64 + n * 16 + l15) * 32 + l4 * 8);
#pragma unroll
        for (int m = 0; m < 4; ++m)
#pragma unroll
            for (int n = 0; n < 4; ++n)
                acc[m][n] = __builtin_amdgcn_mfma_f32_16x16x32_bf16(af[m], bfr[n], acc[m][n], 0, 0, 0);
        __syncthreads();
    }

#pragma unroll
    for (int m = 0; m < 4; ++m) {
        int row_base = m0 + wr * 64 + m * 16 + l4 * 4;
#pragma unroll
        for (int n = 0; n < 4; ++n) {
            int col = n0 + wc * 64 + n * 16 + l15;
#pragma unroll
            for (int r = 0; r < 4; ++r) {
                int row = row_base + r;
                float v = acc[m][n][r];
                if (MODE == 1) {
                    ((float*)Cptr)[(size_t)row * N + col] = v + bias[col];
                } else {
                    if (col < 1024) v *= QSCALE;   // Q pre-scale (n0 uniform; cheap)
                    ((short*)Cptr)[(size_t)row * N + col] = f2bf(v);
                }
            }
        }
    }
}

// ---------------------------------------------------------------------------
// Flash attention v9 = v5 structure (paired strips, 4 waves, 2 barriers/tile)
//  + exp2-domain softmax (Q pre-scaled; bare v_exp_f32)
//  + defer-max rescale (THR=8 in log2 units)
//  + conflict-free layouts from v8 (Vt chunk-XOR, Ps stride 76)
// ---------------------------------------------------------------------------
__device__ __forceinline__ void softmax_phase(
    f32x4 S[4], f32x4 O[4], float* mrow, float* srow,
    int qrow0, int s0, bool diag, int l15, int l4, short* ps) {
    float pmax[4];
#pragma unroll
    for (int r = 0; r < 4; ++r) pmax[r] = -1e30f;
#pragma unroll
    for (int n = 0; n < 4; ++n) {
#pragma unroll
        for (int r = 0; r < 4; ++r) {
            float v = S[n][r];   // already in log2 domain (Q pre-scaled)
            if (diag) {
                int scol = s0 + n * 16 + l15;
                if (scol > qrow0 + r) v = -1e30f;
            }
            S[n][r] = v;
            pmax[r] = fmaxf(pmax[r], v);
        }
    }
#pragma unroll
    for (int r = 0; r < 4; ++r) {
        float v = pmax[r];
        v = fmaxf(v, __shfl_xor(v, 1));
        v = fmaxf(v, __shfl_xor(v, 2));
        v = fmaxf(v, __shfl_xor(v, 4));
        v = fmaxf(v, __shfl_xor(v, 8));
        pmax[r] = v;
    }
    // ---- defer-max: skip rescale when max growth <= 8 (P bounded by 2^8) ----
    int ok = (pmax[0] <= mrow[0] + 8.0f) & (pmax[1] <= mrow[1] + 8.0f) &
             (pmax[2] <= mrow[2] + 8.0f) & (pmax[3] <= mrow[3] + 8.0f);
    if (!__all(ok)) {
#pragma unroll
        for (int r = 0; r < 4; ++r) {
            float mnew = fmaxf(mrow[r], pmax[r]);
            float fr = fast_exp2(mrow[r] - mnew);
            mrow[r] = mnew;
            srow[r] *= fr;
#pragma unroll
            for (int n = 0; n < 4; ++n) O[n][r] *= fr;
        }
    }
    float psum[4];
#pragma unroll
    for (int r = 0; r < 4; ++r) psum[r] = 0.0f;
#pragma unroll
    for (int n = 0; n < 4; ++n) {
#pragma unroll
        for (int r = 0; r < 4; ++r) {
            float p = fast_exp2(S[n][r] - mrow[r]);
            psum[r] += p;
            ps[(l4 * 4 + r) * 76 + n * 16 + l15] = f2bf(p);
        }
    }
#pragma unroll
    for (int r = 0; r < 4; ++r) {
        float v = psum[r];
        v += __shfl_xor(v, 1);
        v += __shfl_xor(v, 2);
        v += __shfl_xor(v, 4);
        v += __shfl_xor(v, 8);
        srow[r] += v;
    }
}

__global__ __launch_bounds__(256)
void attn_v9(const short* __restrict__ qkv, short* __restrict__ out) {
    const int pi = blockIdx.x;        // 0..15 (strip pair)
    const int bh = blockIdx.y;        // 0..63
    const int b = bh >> 4;
    const int h = bh & 15;
    const int qA0 = pi * 64;
    const int qB0 = (31 - pi) * 64;
    const int ntA = pi + 1;
    const int ntB = 32 - pi;
    const int tid = threadIdx.x;
    const int wave = tid >> 6;
    const int lane = tid & 63;
    const int l15 = lane & 15, l4 = lane >> 4;

    __shared__ short Vt[64][64];        // Vt[d][s], chunk-XOR swizzled
    __shared__ short Ps[4][2][16][76];  // per-wave, per-strip P buffer

    const size_t rs = 3 * C_;
    const short* qbA = qkv + ((size_t)b * T_ + qA0) * rs + h * 64;
    const short* qbB = qkv + ((size_t)b * T_ + qB0) * rs + h * 64;
    const short* kb  = qkv + (size_t)b * T_ * rs + C_ + h * 64;
    const short* vb  = qkv + (size_t)b * T_ * rs + 2 * C_ + h * 64;

    bf16x8 aqA0 = *(const bf16x8*)(qbA + (size_t)(wave * 16 + l15) * rs + l4 * 8);
    bf16x8 aqA1 = *(const bf16x8*)(qbA + (size_t)(wave * 16 + l15) * rs + 32 + l4 * 8);
    bf16x8 aqB0 = *(const bf16x8*)(qbB + (size_t)(wave * 16 + l15) * rs + l4 * 8);
    bf16x8 aqB1 = *(const bf16x8*)(qbB + (size_t)(wave * 16 + l15) * rs + 32 + l4 * 8);

    f32x4 OA[4] = {}, OB[4] = {};
    float mA[4], sA[4], mB[4], sB[4];
#pragma unroll
    for (int r = 0; r < 4; ++r) { mA[r] = mB[r] = -1e30f; sA[r] = sB[r] = 0.0f; }

    short* psB = &Ps[wave][0][0][0];
    short* psA = &Ps[wave][1][0][0];

    for (int t = 0; t < ntB; ++t) {
        const int s0 = t * 64;
        const bool actA = (t < ntA);
        __syncthreads();  // all waves done reading Vt from previous tile

        // ---- stage V (coalesced gather, chunk-XOR swizzled b128 writes) ----
#pragma unroll
        for (int p = 0; p < 2; ++p) {
            int e = p * 256 + tid;
            int d = e & 63, sc = e >> 6;
            bf16x8 v;
#pragma unroll
            for (int j = 0; j < 8; ++j)
                v[j] = vb[(size_t)(s0 + sc * 8 + j) * rs + d];
            *(bf16x8*)&Vt[d][(sc ^ (d & 7)) * 8] = v;
        }

        // ---- K fragments (shared by both strips) ----
        bf16x8 bk0[4], bk1[4];
#pragma unroll
        for (int n = 0; n < 4; ++n) {
            const short* kr = kb + (size_t)(s0 + n * 16 + l15) * rs;
            bk0[n] = *(const bf16x8*)(kr + l4 * 8);
            bk1[n] = *(const bf16x8*)(kr + 32 + l4 * 8);
        }

        // ---- strip B: S = Q K^T + softmax ----
        f32x4 S[4];
#pragma unroll
        for (int n = 0; n < 4; ++n) {
            f32x4 z = {};
            z = __builtin_amdgcn_mfma_f32_16x16x32_bf16(aqB0, bk0[n], z, 0, 0, 0);
            S[n] = __builtin_amdgcn_mfma_f32_16x16x32_bf16(aqB1, bk1[n], z, 0, 0, 0);
        }
        softmax_phase(S, OB, mB, sB, qB0 + wave * 16 + l4 * 4, s0, s0 == qB0,
                      l15, l4, psB);

        // ---- strip A ----
        if (actA) {
            f32x4 SA[4];
#pragma unroll
            for (int n = 0; n < 4; ++n) {
                f32x4 z = {};
                z = __builtin_amdgcn_mfma_f32_16x16x32_bf16(aqA0, bk0[n], z, 0, 0, 0);
                SA[n] = __builtin_amdgcn_mfma_f32_16x16x32_bf16(aqA1, bk1[n], z, 0, 0, 0);
            }
            softmax_phase(SA, OA, mA, sA, qA0 + wave * 16 + l4 * 4, s0, s0 == qA0,
                          l15, l4, psA);
        }

        __syncthreads();  // Vt staged; Ps writes drained by barrier

        // ---- PV strip B (swizzled Vt reads) ----
        bf16x8 apB0 = *(const bf16x8*)(psB + l15 * 76 + l4 * 8);
        bf16x8 apB1 = *(const bf16x8*)(psB + l15 * 76 + 32 + l4 * 8);
#pragma unroll
        for (int n = 0; n < 4; ++n) {
            const short* vrow = &Vt[n * 16 + l15][0];
            bf16x8 bv0 = *(const bf16x8*)(vrow + ((l4 ^ (l15 & 7)) * 8));
            bf16x8 bv1 = *(const bf16x8*)(vrow + (((l4 + 4) ^ (l15 & 7)) * 8));
            OB[n] = __builtin_amdgcn_mfma_f32_16x16x32_bf16(apB0, bv0, OB[n], 0, 0, 0);
            OB[n] = __builtin_amdgcn_mfma_f32_16x16x32_bf16(apB1, bv1, OB[n], 0, 0, 0);
        }
        // ---- PV strip A ----
        if (actA) {
            bf16x8 apA0 = *(const bf16x8*)(psA + l15 * 76 + l4 * 8);
            bf16x8 apA1 = *(const bf16x8*)(psA + l15 * 76 + 32 + l4 * 8);
#pragma unroll
            for (int n = 0; n < 4; ++n) {
                const short* vrow = &Vt[n * 16 + l15][0];
                bf16x8 bv0 = *(const bf16x8*)(vrow + ((l4 ^ (l15 & 7)) * 8));
                bf16x8 bv1 = *(const bf16x8*)(vrow + (((l4 + 4) ^ (l15 & 7)) * 8));
                OA[n] = __builtin_amdgcn_mfma_f32_16x16x32_bf16(apA0, bv0, OA[n], 0, 0, 0);
                OA[n] = __builtin_amdgcn_mfma_f32_16x16x32_bf16(apA1, bv1, OA[n], 0, 0, 0);
            }
        }
    }

    // ---- normalize + store both strips ----
#pragma unroll
    for (int r = 0; r < 4; ++r) {
        int rowB = qB0 + wave * 16 + l4 * 4 + r;
        int rowA = qA0 + wave * 16 + l4 * 4 + r;
        float invB = 1.0f / sB[r];
        float invA = 1.0f / sA[r];
        size_t obB = ((size_t)b * T_ + rowB) * C_ + h * 64;
        size_t obA = ((size_t)b * T_ + rowA) * C_ + h * 64;
#pragma unroll
        for (int n = 0; n < 4; ++n) {
            out[obB + n * 16 + l15] = f2bf(OB[n][r] * invB);
            out[obA + n * 16 + l15] = f2bf(OA[n][r] * invA);
        }
    }
}

// ---------------------------------------------------------------------------
extern "C" void kernel_launch(void* const* d_in, const int* in_sizes, int n_in,
                              void* d_out, int out_size, void* d_ws, size_t ws_size,
                              hipStream_t stream) {
    const float* x     = (const float*)d_in[0];
    const float* wq    = (const float*)d_in[1];
    const float* wk    = (const float*)d_in[2];
    const float* wv    = (const float*)d_in[3];
    const float* wproj = (const float*)d_in[4];
    const float* bproj = (const float*)d_in[5];
    float* out = (float*)d_out;

    // workspace layout (shorts): wqkv_t | wproj_t | qkv | attn_b (also xb)
    short* wqkv_t  = (short*)d_ws;                  // 3072*1024
    short* wproj_t = wqkv_t + 3072 * 1024;          // 1024*1024
    short* qkv_b   = wproj_t + 1024 * 1024;         // 8192*3072
    short* attn_b  = qkv_b + (size_t)8192 * 3072;   // 8192*1024 (xb aliased here)
    short* xb      = attn_b;                        // x bf16, dead after gemm1
    // total = 75,497,472 bytes

    pack_x<<<4096, 256, 0, stream>>>(x, xb);
    pack_wqkv<<<1536, 256, 0, stream>>>(wq, wk, wv, wqkv_t);
    pack_wproj<<<512, 256, 0, stream>>>(wproj, wproj_t);

    // QKV projection: [8192,1024] x [1024,3072] -> bf16 (Q cols pre-scaled)
    gemm_lds<2><<<dim3(24, 64), 256, 0, stream>>>(
        xb, wqkv_t, qkv_b, nullptr, 8192, 3072, 1024);

    // flash attention, causal-paired strips
    attn_v9<<<dim3(16, 64), 256, 0, stream>>>(qkv_b, attn_b);

    // output projection: [8192,1024] x [1024,1024] + bias -> fp32
    gemm_lds<1><<<dim3(8, 64), 256, 0, stream>>>(
        attn_b, wproj_t, out, bproj, 8192, 1024, 1024);
}